// Round 3
// baseline (1194.836 us; speedup 1.0000x reference)
//
#include <hip/hip_runtime.h>
#include <hip/hip_bf16.h>
#include <stdint.h>

#define N_AL 9
#define N_EN 10
#define D_OWN 96
#define D_AL 64
#define D_EN 65
#define BROWS 65536

// ws byte layout
#define WS_P0 0        // 48 KB: phase0 frags (16 tiles x 3 ks x 64 lanes x 16B)
#define WS_B0 49152    // 1 KB : bias0 = [bq*QS (128) | bown (128)] f32
#define WS_P1 50176    // 36 KB region: [bpack1 32768][bav 512][pad]
#define WS_P2 87040    // 36 KB region: [bpack2 32768][w64cat 1024][bev 512][pad]
#define REGION 36864

#define QSCALE (0.17677669529663688f * 1.4426950408889634f)  // 1/sqrt(32) * log2(e)

typedef __attribute__((ext_vector_type(8))) short short8;
typedef __attribute__((ext_vector_type(4))) float f32x4;
typedef __attribute__((ext_vector_type(4), aligned(4))) float f32x4u;  // dword-aligned vector load
typedef __attribute__((address_space(1))) const unsigned guint;
typedef __attribute__((address_space(3))) unsigned luint;

static __device__ __forceinline__ unsigned cvtpk(float lo, float hi) {
    unsigned r;
    asm("v_cvt_pk_bf16_f32 %0, %1, %2" : "=v"(r) : "v"(lo), "v"(hi));
    return r;
}
static __device__ __forceinline__ float bflo(unsigned u) { return __builtin_bit_cast(float, u << 16); }
static __device__ __forceinline__ float bfhi(unsigned u) { return __builtin_bit_cast(float, u & 0xffff0000u); }

static __device__ __forceinline__ short8 pack8(f32x4 a, f32x4 b) {
    union { unsigned u[4]; short8 s; } t;
    t.u[0] = cvtpk(a[0], a[1]); t.u[1] = cvtpk(a[2], a[3]);
    t.u[2] = cvtpk(b[0], b[1]); t.u[3] = cvtpk(b[2], b[3]);
    return t.s;
}
static __device__ __forceinline__ short f2bf1(float x) { return (short)(cvtpk(x, 0.0f) & 0xffffu); }

// ---------------- weight packing kernel (runs once per launch, 31 blocks) ----------------
__global__ void pack_weights(const float* __restrict__ Wq,  const float* __restrict__ bq,
                             const float* __restrict__ Wak, const float* __restrict__ Wav,
                             const float* __restrict__ bav, const float* __restrict__ Wek,
                             const float* __restrict__ Wev, const float* __restrict__ bev,
                             const float* __restrict__ Wown,const float* __restrict__ bown,
                             char* __restrict__ ws)
{
    int id = blockIdx.x * 256 + threadIdx.x;
    if (id < 7168) {
        const float *W0, *W1; int KS; short* dst; int f; bool isP0 = false;
        if (id < 3072)      { W0 = Wq;  W1 = Wown; KS = 3; dst = (short*)(ws + WS_P0); f = id; isP0 = true; }
        else if (id < 5120) { W0 = Wak; W1 = Wav;  KS = 2; dst = (short*)(ws + WS_P1); f = id - 3072; }
        else                { W0 = Wek; W1 = Wev;  KS = 2; dst = (short*)(ws + WS_P2); f = id - 5120; }
        int lane = f & 63, ks = (f >> 6) % KS, tile = f / (KS * 64);
        int col = tile * 16 + (lane & 15), k0 = ks * 32 + (lane >> 4) * 8;
        const float* W = (col < 128) ? W0 : W1;
        float scl = (isP0 && col < 128) ? QSCALE : 1.0f;   // fold softmax scale*log2e into Wq
        int c = col & 127;
        short8 v;
        #pragma unroll
        for (int i = 0; i < 8; ++i) v[i] = f2bf1(W[(k0 + i) * 128 + c] * scl);
        *(short8*)(dst + (size_t)f * 8) = v;
    } else if (id < 7936) {
        int j = id - 7168;
        float* b0  = (float*)(ws + WS_B0);
        float* bV1 = (float*)(ws + WS_P1 + 32768);
        float* w64 = (float*)(ws + WS_P2 + 32768);
        float* bV2 = (float*)(ws + WS_P2 + 33792);
        if      (j < 128) b0[j] = bq[j] * QSCALE;
        else if (j < 256) b0[j] = bown[j - 128];
        else if (j < 384) w64[j - 256] = Wek[64 * 128 + (j - 256)];
        else if (j < 512) w64[j - 256] = Wev[64 * 128 + (j - 384)];
        else if (j < 640) bV1[j - 512] = bav[j - 512];
        else              bV2[j - 640] = bev[j - 640];
    }
}

// ---------------- 36 KB linear global->LDS stage (16B direct-to-LDS) ----------------
static __device__ __forceinline__ void stage36(const char* src, char* smem, int wid, int lane) {
    #pragma unroll
    for (int c = 0; c < 9; ++c) {
        int off = (wid * 9 + c) * 1024;
        __builtin_amdgcn_global_load_lds((guint*)(src + off + lane * 16),
                                         (luint*)(smem + off), 16, 0, 0);
    }
}

// ---------------- raw A-row loads (prefetchable) ----------------
static __device__ __forceinline__ void loadAllyRaw(const float* __restrict__ ally,
                                                   int arow, int kgrp, int e, f32x4* v) {
    const float* ap = ally + ((size_t)arow * N_AL + e) * D_AL + kgrp * 8;
    v[0] = *(const f32x4*)(ap);
    v[1] = *(const f32x4*)(ap + 4);
    v[2] = *(const f32x4*)(ap + 32);
    v[3] = *(const f32x4*)(ap + 36);
}

static __device__ __forceinline__ void loadEnemyRaw(const float* __restrict__ enemy,
                                                    int arow, int row0, int kgrp, int e,
                                                    f32x4* v, float* x64) {
    const float* ap = enemy + ((size_t)arow * N_EN + e) * D_EN + kgrp * 8;
    v[0] = *(const f32x4u*)(ap);
    v[1] = *(const f32x4u*)(ap + 4);
    v[2] = *(const f32x4u*)(ap + 32);
    v[3] = *(const f32x4u*)(ap + 36);
    #pragma unroll
    for (int r = 0; r < 4; ++r)
        x64[r] = enemy[((size_t)(row0 + kgrp * 4 + r) * N_EN + e) * D_EN + 64];
}

// ---------------- one entity's K-attn-V update (head-pair split) ----------------
template <bool X64>
static __device__ __forceinline__ void entity_step(
    const short8* afr, const float* x64, const unsigned* qq,
    float (&accn)[2][4][4], float (&accd)[4][4],
    const short* bpk, const float* w64lds, int lane)
{
    const int lrow = lane & 15;
    #pragma unroll
    for (int hp = 0; hp < 2; ++hp) {
        f32x4 acc4[4];
        #pragma unroll
        for (int j = 0; j < 4; ++j) {
            if (X64) {
                float w = w64lds[(4 * hp + j) * 16 + lrow];
                #pragma unroll
                for (int r = 0; r < 4; ++r) acc4[j][r] = x64[r] * w;
            } else {
                #pragma unroll
                for (int r = 0; r < 4; ++r) acc4[j][r] = 0.0f;
            }
        }
        #pragma unroll
        for (int ks = 0; ks < 2; ++ks)
            #pragma unroll
            for (int j = 0; j < 4; ++j) {
                short8 bfr = *(const short8*)(bpk + (size_t)(((4 * hp + j) * 2 + ks) * 64 + lane) * 8);
                acc4[j] = __builtin_amdgcn_mfma_f32_16x16x32_bf16(afr[ks], bfr, acc4[j], 0, 0, 0);
            }
        float p0[4] = {0, 0, 0, 0}, p1[4] = {0, 0, 0, 0};
        #pragma unroll
        for (int j = 0; j < 4; ++j) {
            int t = 4 * hp + j;
            float* pp = (j < 2) ? p0 : p1;
            #pragma unroll
            for (int pr = 0; pr < 2; ++pr) {
                unsigned u = qq[t * 2 + pr];
                pp[2 * pr]     += bflo(u) * acc4[j][2 * pr];
                pp[2 * pr + 1] += bfhi(u) * acc4[j][2 * pr + 1];
            }
        }
        #pragma unroll
        for (int m = 1; m <= 8; m <<= 1) {
            #pragma unroll
            for (int r = 0; r < 4; ++r) {
                p0[r] += __shfl_xor(p0[r], m, 64);
                p1[r] += __shfl_xor(p1[r], m, 64);
            }
        }
        float s0[4], s1[4];
        #pragma unroll
        for (int r = 0; r < 4; ++r) {
            s0[r] = __builtin_amdgcn_exp2f(p0[r]);   // scale*log2e pre-folded into q
            s1[r] = __builtin_amdgcn_exp2f(p1[r]);
            accd[2 * hp][r] += s0[r]; accd[2 * hp + 1][r] += s1[r];
        }
        #pragma unroll
        for (int j = 0; j < 4; ++j) {
            if (X64) {
                float w = w64lds[128 + (4 * hp + j) * 16 + lrow];
                #pragma unroll
                for (int r = 0; r < 4; ++r) acc4[j][r] = x64[r] * w;
            } else {
                #pragma unroll
                for (int r = 0; r < 4; ++r) acc4[j][r] = 0.0f;
            }
        }
        #pragma unroll
        for (int ks = 0; ks < 2; ++ks)
            #pragma unroll
            for (int j = 0; j < 4; ++j) {
                short8 bfr = *(const short8*)(bpk + (size_t)(((8 + 4 * hp + j) * 2 + ks) * 64 + lane) * 8);
                acc4[j] = __builtin_amdgcn_mfma_f32_16x16x32_bf16(afr[ks], bfr, acc4[j], 0, 0, 0);
            }
        #pragma unroll
        for (int j = 0; j < 4; ++j) {
            const float* s = (j < 2) ? s0 : s1;
            #pragma unroll
            for (int r = 0; r < 4; ++r) accn[hp][j][r] += s[r] * acc4[j][r];
        }
    }
}

static __device__ __forceinline__ void write_attn(float* __restrict__ out, int row0, int kgrp,
                                                  int lrow, int coloff,
                                                  const float (&accn)[2][4][4],
                                                  const float (&accd)[4][4],
                                                  const float* bVlds)
{
    float inv[4][4];
    #pragma unroll
    for (int h = 0; h < 4; ++h)
        #pragma unroll
        for (int r = 0; r < 4; ++r) inv[h][r] = 1.0f / accd[h][r];
    #pragma unroll
    for (int hp = 0; hp < 2; ++hp)
        #pragma unroll
        for (int j = 0; j < 4; ++j) {
            int col = (4 * hp + j) * 16 + lrow;
            float bb = bVlds[col];
            #pragma unroll
            for (int r = 0; r < 4; ++r)
                out[(size_t)(row0 + kgrp * 4 + r) * 384 + coloff + col] =
                    accn[hp][j][r] * inv[2 * hp + (j >> 1)][r] + bb;
        }
}

// ---------------- main fused kernel ----------------
__global__ __launch_bounds__(256, 4)
void TrSFRNNAgent_fused(const float* __restrict__ own,
                        const float* __restrict__ ally,
                        const float* __restrict__ enemy,
                        const char* __restrict__ ws,
                        float* __restrict__ out)
{
    __shared__ __align__(16) char smem[REGION];
    const int tid = threadIdx.x, lane = tid & 63, wid = tid >> 6;
    const int row0 = blockIdx.x * 64 + wid * 16;
    const int lrow = lane & 15, kgrp = lane >> 4;
    const int arow = row0 + lrow;

    // stage phase-1 weights into LDS; hides under phase-0 compute
    stage36(ws + WS_P1, smem, wid, lane);

    // prefetch ally entity 0 (consumed after phase 0)
    f32x4 prefA[4];
    loadAllyRaw(ally, arow, kgrp, 0, prefA);

    // ---------------- Phase 0: own_obs -> q (bf16, scale folded) + own_feature ----------------
    unsigned qq[16];
    {
        short8 afr0[3];
        {
            const float* ap = own + (size_t)arow * D_OWN + kgrp * 8;
            #pragma unroll
            for (int ks = 0; ks < 3; ++ks) {
                f32x4 a = *(const f32x4*)(ap + ks * 32);
                f32x4 b = *(const f32x4*)(ap + ks * 32 + 4);
                afr0[ks] = pack8(a, b);
            }
        }
        const short* bp0 = (const short*)(ws + WS_P0);
        const float* b0  = (const float*)(ws + WS_B0);
        #pragma unroll
        for (int pass = 0; pass < 2; ++pass) {       // 8 tiles per pass: half the acc regs
            f32x4 acc[8];
            #pragma unroll
            for (int t = 0; t < 8; ++t)
                #pragma unroll
                for (int r = 0; r < 4; ++r) acc[t][r] = 0.0f;
            #pragma unroll
            for (int ks = 0; ks < 3; ++ks)
                #pragma unroll
                for (int t = 0; t < 8; ++t) {
                    short8 bfr = *(const short8*)(bp0 + (size_t)(((pass * 8 + t) * 3 + ks) * 64 + lane) * 8);
                    acc[t] = __builtin_amdgcn_mfma_f32_16x16x32_bf16(afr0[ks], bfr, acc[t], 0, 0, 0);
                }
            if (pass == 0) {
                #pragma unroll
                for (int t = 0; t < 8; ++t) {
                    float bb = b0[t * 16 + lrow];   // pre-scaled
                    qq[t * 2]     = cvtpk(acc[t][0] + bb, acc[t][1] + bb);
                    qq[t * 2 + 1] = cvtpk(acc[t][2] + bb, acc[t][3] + bb);
                }
            } else {
                #pragma unroll
                for (int t = 0; t < 8; ++t) {
                    float bb = b0[128 + t * 16 + lrow];
                    #pragma unroll
                    for (int r = 0; r < 4; ++r)
                        out[(size_t)(row0 + kgrp * 4 + r) * 384 + t * 16 + lrow] = acc[t][r] + bb;
                }
            }
        }
    }
    __syncthreads();   // phase-1 LDS ready

    // ---------------- Phase 1: allies (software-pipelined) ----------------
    f32x4 prefE[4]; float x64e[4];
    {
        float accn[2][4][4] = {{{0}}}; float accd[4][4] = {{0}};
        #pragma unroll
        for (int e = 0; e < N_AL; ++e) {
            short8 afr[2];
            afr[0] = pack8(prefA[0], prefA[1]);
            afr[1] = pack8(prefA[2], prefA[3]);
            if (e + 1 < N_AL) loadAllyRaw(ally, arow, kgrp, e + 1, prefA);
            else              loadEnemyRaw(enemy, arow, row0, kgrp, 0, prefE, x64e);
            entity_step<false>(afr, nullptr, qq, accn, accd, (const short*)smem, nullptr, lane);
        }
        write_attn(out, row0, kgrp, lrow, 128, accn, accd, (const float*)(smem + 32768));
    }
    __syncthreads();                       // all waves done reading phase-1 LDS
    stage36(ws + WS_P2, smem, wid, lane);  // re-stage for phase 2 (prefE survives in regs)
    __syncthreads();

    // ---------------- Phase 2: enemies (K=64 staged + k64 rank-1 via acc init) ----------------
    {
        const float* w64lds = (const float*)(smem + 32768);
        float accn[2][4][4] = {{{0}}}; float accd[4][4] = {{0}};
        #pragma unroll
        for (int e = 0; e < N_EN; ++e) {
            short8 afr[2];
            afr[0] = pack8(prefE[0], prefE[1]);
            afr[1] = pack8(prefE[2], prefE[3]);
            float xc[4];
            #pragma unroll
            for (int r = 0; r < 4; ++r) xc[r] = x64e[r];
            if (e + 1 < N_EN) loadEnemyRaw(enemy, arow, row0, kgrp, e + 1, prefE, x64e);
            entity_step<true>(afr, xc, qq, accn, accd, (const short*)smem, w64lds, lane);
        }
        write_attn(out, row0, kgrp, lrow, 256, accn, accd, (const float*)(smem + 33792));
    }
}

extern "C" void kernel_launch(void* const* d_in, const int* in_sizes, int n_in,
                              void* d_out, int out_size, void* d_ws, size_t ws_size,
                              hipStream_t stream)
{
    (void)in_sizes; (void)n_in; (void)out_size; (void)ws_size;
    const float* own   = (const float*)d_in[0];
    const float* ally  = (const float*)d_in[1];
    const float* enemy = (const float*)d_in[2];
    const float* Wq    = (const float*)d_in[3];
    const float* bq    = (const float*)d_in[4];
    const float* Wak   = (const float*)d_in[5];
    const float* Wav   = (const float*)d_in[7];
    const float* bav   = (const float*)d_in[8];
    const float* Wek   = (const float*)d_in[9];
    const float* Wev   = (const float*)d_in[11];
    const float* bev   = (const float*)d_in[12];
    const float* Wown  = (const float*)d_in[13];
    const float* bown  = (const float*)d_in[14];

    pack_weights<<<31, 256, 0, stream>>>(Wq, bq, Wak, Wav, bav, Wek, Wev, bev, Wown, bown,
                                         (char*)d_ws);
    TrSFRNNAgent_fused<<<BROWS / 64, 256, 0, stream>>>(own, ally, enemy,
                                                       (const char*)d_ws, (float*)d_out);
}

// Round 4
// 268.824 us; speedup vs baseline: 4.4447x; 4.4447x over previous
//
#include <hip/hip_runtime.h>
#include <hip/hip_bf16.h>
#include <stdint.h>

#define N_AL 9
#define N_EN 10
#define D_OWN 96
#define D_AL 64
#define D_EN 65
#define BROWS 65536

// ws byte layout
#define WS_P0 0        // 48 KB: phase0 frags (16 tiles x 3 ks x 64 lanes x 16B)
#define WS_B0 49152    // 1 KB : bias0 = [bq*QS (128) | bown (128)] f32
#define WS_P1 50176    // 36 KB region: [bpack1 32768][bav 512][pad]
#define WS_P2 87040    // 36 KB region: [bpack2 32768][w64cat 1024][bev 512][pad]
#define REGION 36864

#define QSCALE (0.17677669529663688f * 1.4426950408889634f)  // 1/sqrt(32) * log2(e)

typedef __attribute__((ext_vector_type(8))) short short8;
typedef __attribute__((ext_vector_type(4))) float f32x4;
typedef __attribute__((ext_vector_type(4), aligned(4))) float f32x4u;  // dword-aligned vector load
typedef __attribute__((address_space(1))) const unsigned guint;
typedef __attribute__((address_space(3))) unsigned luint;

static __device__ __forceinline__ unsigned cvtpk(float lo, float hi) {
    unsigned r;
    asm("v_cvt_pk_bf16_f32 %0, %1, %2" : "=v"(r) : "v"(lo), "v"(hi));
    return r;
}
static __device__ __forceinline__ float bflo(unsigned u) { return __builtin_bit_cast(float, u << 16); }
static __device__ __forceinline__ float bfhi(unsigned u) { return __builtin_bit_cast(float, u & 0xffff0000u); }

static __device__ __forceinline__ short8 pack8(f32x4 a, f32x4 b) {
    union { unsigned u[4]; short8 s; } t;
    t.u[0] = cvtpk(a[0], a[1]); t.u[1] = cvtpk(a[2], a[3]);
    t.u[2] = cvtpk(b[0], b[1]); t.u[3] = cvtpk(b[2], b[3]);
    return t.s;
}
static __device__ __forceinline__ short f2bf1(float x) { return (short)(cvtpk(x, 0.0f) & 0xffffu); }

// ---------------- weight packing kernel (runs once per launch, 31 blocks) ----------------
__global__ void pack_weights(const float* __restrict__ Wq,  const float* __restrict__ bq,
                             const float* __restrict__ Wak, const float* __restrict__ Wav,
                             const float* __restrict__ bav, const float* __restrict__ Wek,
                             const float* __restrict__ Wev, const float* __restrict__ bev,
                             const float* __restrict__ Wown,const float* __restrict__ bown,
                             char* __restrict__ ws)
{
    int id = blockIdx.x * 256 + threadIdx.x;
    if (id < 7168) {
        const float *W0, *W1; int KS; short* dst; int f; bool isP0 = false;
        if (id < 3072)      { W0 = Wq;  W1 = Wown; KS = 3; dst = (short*)(ws + WS_P0); f = id; isP0 = true; }
        else if (id < 5120) { W0 = Wak; W1 = Wav;  KS = 2; dst = (short*)(ws + WS_P1); f = id - 3072; }
        else                { W0 = Wek; W1 = Wev;  KS = 2; dst = (short*)(ws + WS_P2); f = id - 5120; }
        int lane = f & 63, ks = (f >> 6) % KS, tile = f / (KS * 64);
        int col = tile * 16 + (lane & 15), k0 = ks * 32 + (lane >> 4) * 8;
        const float* W = (col < 128) ? W0 : W1;
        float scl = (isP0 && col < 128) ? QSCALE : 1.0f;   // fold softmax scale*log2e into Wq
        int c = col & 127;
        short8 v;
        #pragma unroll
        for (int i = 0; i < 8; ++i) v[i] = f2bf1(W[(k0 + i) * 128 + c] * scl);
        *(short8*)(dst + (size_t)f * 8) = v;
    } else if (id < 7936) {
        int j = id - 7168;
        float* b0  = (float*)(ws + WS_B0);
        float* bV1 = (float*)(ws + WS_P1 + 32768);
        float* w64 = (float*)(ws + WS_P2 + 32768);
        float* bV2 = (float*)(ws + WS_P2 + 33792);
        if      (j < 128) b0[j] = bq[j] * QSCALE;
        else if (j < 256) b0[j] = bown[j - 128];
        else if (j < 384) w64[j - 256] = Wek[64 * 128 + (j - 256)];
        else if (j < 512) w64[j - 256] = Wev[64 * 128 + (j - 384)];
        else if (j < 640) bV1[j - 512] = bav[j - 512];
        else              bV2[j - 640] = bev[j - 640];
    }
}

// ---------------- 36 KB linear global->LDS stage (16B direct-to-LDS) ----------------
static __device__ __forceinline__ void stage36(const char* src, char* smem, int wid, int lane) {
    #pragma unroll
    for (int c = 0; c < 9; ++c) {
        int off = (wid * 9 + c) * 1024;
        __builtin_amdgcn_global_load_lds((guint*)(src + off + lane * 16),
                                         (luint*)(smem + off), 16, 0, 0);
    }
}

// ---------------- raw A-row loads (prefetchable) ----------------
static __device__ __forceinline__ void loadAllyRaw(const float* __restrict__ ally,
                                                   int arow, int kgrp, int e, f32x4* v) {
    const float* ap = ally + ((size_t)arow * N_AL + e) * D_AL + kgrp * 8;
    v[0] = *(const f32x4*)(ap);
    v[1] = *(const f32x4*)(ap + 4);
    v[2] = *(const f32x4*)(ap + 32);
    v[3] = *(const f32x4*)(ap + 36);
}

static __device__ __forceinline__ void loadEnemyRaw(const float* __restrict__ enemy,
                                                    int arow, int row0, int kgrp, int e,
                                                    f32x4* v, float* x64) {
    const float* ap = enemy + ((size_t)arow * N_EN + e) * D_EN + kgrp * 8;
    v[0] = *(const f32x4u*)(ap);
    v[1] = *(const f32x4u*)(ap + 4);
    v[2] = *(const f32x4u*)(ap + 32);
    v[3] = *(const f32x4u*)(ap + 36);
    #pragma unroll
    for (int r = 0; r < 4; ++r)
        x64[r] = enemy[((size_t)(row0 + kgrp * 4 + r) * N_EN + e) * D_EN + 64];
}

// ---------------- one entity's K-attn-V update (head-pair split, sharded denom) ----------------
template <bool X64>
static __device__ __forceinline__ void entity_step(
    const short8* afr, const float* x64, const unsigned* qq,
    float (&accn)[2][4][4], float (&accd4)[4], const float (&hm)[4],
    const short* bpk, const float* w64lds, int lane)
{
    const int lrow = lane & 15;
    #pragma unroll
    for (int hp = 0; hp < 2; ++hp) {
        f32x4 acc4[4];
        #pragma unroll
        for (int j = 0; j < 4; ++j) {
            if (X64) {
                float w = w64lds[(4 * hp + j) * 16 + lrow];
                #pragma unroll
                for (int r = 0; r < 4; ++r) acc4[j][r] = x64[r] * w;
            } else {
                #pragma unroll
                for (int r = 0; r < 4; ++r) acc4[j][r] = 0.0f;
            }
        }
        #pragma unroll
        for (int ks = 0; ks < 2; ++ks)
            #pragma unroll
            for (int j = 0; j < 4; ++j) {
                short8 bfr = *(const short8*)(bpk + (size_t)(((4 * hp + j) * 2 + ks) * 64 + lane) * 8);
                acc4[j] = __builtin_amdgcn_mfma_f32_16x16x32_bf16(afr[ks], bfr, acc4[j], 0, 0, 0);
            }
        float p0[4] = {0, 0, 0, 0}, p1[4] = {0, 0, 0, 0};
        #pragma unroll
        for (int j = 0; j < 4; ++j) {
            int t = 4 * hp + j;
            float* pp = (j < 2) ? p0 : p1;
            #pragma unroll
            for (int pr = 0; pr < 2; ++pr) {
                unsigned u = qq[t * 2 + pr];
                pp[2 * pr]     += bflo(u) * acc4[j][2 * pr];
                pp[2 * pr + 1] += bfhi(u) * acc4[j][2 * pr + 1];
            }
        }
        #pragma unroll
        for (int m = 1; m <= 8; m <<= 1) {
            #pragma unroll
            for (int r = 0; r < 4; ++r) {
                p0[r] += __shfl_xor(p0[r], m, 64);
                p1[r] += __shfl_xor(p1[r], m, 64);
            }
        }
        float s0[4], s1[4];
        #pragma unroll
        for (int r = 0; r < 4; ++r) {
            s0[r] = __builtin_amdgcn_exp2f(p0[r]);   // scale*log2e pre-folded into q
            s1[r] = __builtin_amdgcn_exp2f(p1[r]);
            accd4[r] += hm[2 * hp] * s0[r] + hm[2 * hp + 1] * s1[r];  // lane keeps head lane&3 only
        }
        #pragma unroll
        for (int j = 0; j < 4; ++j) {
            if (X64) {
                float w = w64lds[128 + (4 * hp + j) * 16 + lrow];
                #pragma unroll
                for (int r = 0; r < 4; ++r) acc4[j][r] = x64[r] * w;
            } else {
                #pragma unroll
                for (int r = 0; r < 4; ++r) acc4[j][r] = 0.0f;
            }
        }
        #pragma unroll
        for (int ks = 0; ks < 2; ++ks)
            #pragma unroll
            for (int j = 0; j < 4; ++j) {
                short8 bfr = *(const short8*)(bpk + (size_t)(((8 + 4 * hp + j) * 2 + ks) * 64 + lane) * 8);
                acc4[j] = __builtin_amdgcn_mfma_f32_16x16x32_bf16(afr[ks], bfr, acc4[j], 0, 0, 0);
            }
        #pragma unroll
        for (int j = 0; j < 4; ++j) {
            const float* s = (j < 2) ? s0 : s1;
            #pragma unroll
            for (int r = 0; r < 4; ++r) accn[hp][j][r] += s[r] * acc4[j][r];
        }
    }
}

static __device__ __forceinline__ void write_attn(float* __restrict__ out, int row0, int kgrp,
                                                  int lrow, int coloff,
                                                  const float (&accn)[2][4][4],
                                                  const float (&accd4)[4],
                                                  const float* bVlds, int lane)
{
    // gather all 4 heads' denominators from the lanes sharding them (same 16-group)
    float inv[4][4];
    #pragma unroll
    for (int h = 0; h < 4; ++h)
        #pragma unroll
        for (int r = 0; r < 4; ++r)
            inv[h][r] = 1.0f / __shfl(accd4[r], (lane & ~3) | h, 64);
    #pragma unroll
    for (int hp = 0; hp < 2; ++hp)
        #pragma unroll
        for (int j = 0; j < 4; ++j) {
            int col = (4 * hp + j) * 16 + lrow;
            float bb = bVlds[col];
            #pragma unroll
            for (int r = 0; r < 4; ++r)
                __builtin_nontemporal_store(
                    accn[hp][j][r] * inv[2 * hp + (j >> 1)][r] + bb,
                    &out[(size_t)(row0 + kgrp * 4 + r) * 384 + coloff + col]);
        }
}

// ---------------- main fused kernel: 4 waves x 16 rows, grid 1024 = 4 blocks/CU resident ----------------
__global__ __launch_bounds__(256, 4)
void TrSFRNNAgent_fused(const float* __restrict__ own,
                        const float* __restrict__ ally,
                        const float* __restrict__ enemy,
                        const char* __restrict__ ws,
                        float* __restrict__ out)
{
    __shared__ __align__(16) char smem[REGION];
    const int tid = threadIdx.x, lane = tid & 63, wid = tid >> 6;
    const int row0 = blockIdx.x * 64 + wid * 16;
    const int lrow = lane & 15, kgrp = lane >> 4;
    const int arow = row0 + lrow;
    float hm[4];
    #pragma unroll
    for (int h = 0; h < 4; ++h) hm[h] = ((lane & 3) == h) ? 1.0f : 0.0f;

    // stage phase-1 weights into LDS; hides under phase-0 compute
    stage36(ws + WS_P1, smem, wid, lane);

    // prefetch ally entity 0 (consumed after phase 0)
    f32x4 prefA[4];
    loadAllyRaw(ally, arow, kgrp, 0, prefA);

    // ---------------- Phase 0: own_obs -> q (bf16, scale folded) + own_feature ----------------
    unsigned qq[16];
    {
        short8 afr0[3];
        {
            const float* ap = own + (size_t)arow * D_OWN + kgrp * 8;
            #pragma unroll
            for (int ks = 0; ks < 3; ++ks) {
                f32x4 a = *(const f32x4*)(ap + ks * 32);
                f32x4 b = *(const f32x4*)(ap + ks * 32 + 4);
                afr0[ks] = pack8(a, b);
            }
        }
        const short* bp0 = (const short*)(ws + WS_P0);
        const float* b0  = (const float*)(ws + WS_B0);
        #pragma unroll
        for (int pass = 0; pass < 2; ++pass) {       // 8 tiles per pass: half the acc regs
            f32x4 acc[8];
            #pragma unroll
            for (int t = 0; t < 8; ++t)
                #pragma unroll
                for (int r = 0; r < 4; ++r) acc[t][r] = 0.0f;
            #pragma unroll
            for (int ks = 0; ks < 3; ++ks)
                #pragma unroll
                for (int t = 0; t < 8; ++t) {
                    short8 bfr = *(const short8*)(bp0 + (size_t)(((pass * 8 + t) * 3 + ks) * 64 + lane) * 8);
                    acc[t] = __builtin_amdgcn_mfma_f32_16x16x32_bf16(afr0[ks], bfr, acc[t], 0, 0, 0);
                }
            if (pass == 0) {
                #pragma unroll
                for (int t = 0; t < 8; ++t) {
                    float bb = b0[t * 16 + lrow];   // pre-scaled
                    qq[t * 2]     = cvtpk(acc[t][0] + bb, acc[t][1] + bb);
                    qq[t * 2 + 1] = cvtpk(acc[t][2] + bb, acc[t][3] + bb);
                }
            } else {
                #pragma unroll
                for (int t = 0; t < 8; ++t) {
                    float bb = b0[128 + t * 16 + lrow];
                    #pragma unroll
                    for (int r = 0; r < 4; ++r)
                        __builtin_nontemporal_store(
                            acc[t][r] + bb,
                            &out[(size_t)(row0 + kgrp * 4 + r) * 384 + t * 16 + lrow]);
                }
            }
        }
    }
    __syncthreads();   // phase-1 LDS ready

    // ---------------- Phase 1: allies (rolled, 1-deep register pipeline) ----------------
    f32x4 prefE[4]; float x64e[4];
    {
        float accn[2][4][4] = {{{0}}}; float accd4[4] = {0, 0, 0, 0};
        #pragma unroll 1
        for (int e = 0; e < N_AL; ++e) {
            short8 afr[2];
            afr[0] = pack8(prefA[0], prefA[1]);
            afr[1] = pack8(prefA[2], prefA[3]);
            if (e + 1 < N_AL) loadAllyRaw(ally, arow, kgrp, e + 1, prefA);
            entity_step<false>(afr, nullptr, qq, accn, accd4, hm, (const short*)smem, nullptr, lane);
        }
        loadEnemyRaw(enemy, arow, row0, kgrp, 0, prefE, x64e);   // hides under stores+barriers
        write_attn(out, row0, kgrp, lrow, 128, accn, accd4, (const float*)(smem + 32768), lane);
    }
    __syncthreads();                       // all waves done reading phase-1 LDS
    stage36(ws + WS_P2, smem, wid, lane);  // re-stage for phase 2 (prefE survives in regs)
    __syncthreads();

    // ---------------- Phase 2: enemies (K=64 staged + k64 rank-1 via acc init) ----------------
    {
        const float* w64lds = (const float*)(smem + 32768);
        float accn[2][4][4] = {{{0}}}; float accd4[4] = {0, 0, 0, 0};
        #pragma unroll 1
        for (int e = 0; e < N_EN; ++e) {
            short8 afr[2];
            afr[0] = pack8(prefE[0], prefE[1]);
            afr[1] = pack8(prefE[2], prefE[3]);
            float xc[4];
            #pragma unroll
            for (int r = 0; r < 4; ++r) xc[r] = x64e[r];
            if (e + 1 < N_EN) loadEnemyRaw(enemy, arow, row0, kgrp, e + 1, prefE, x64e);
            entity_step<true>(afr, xc, qq, accn, accd4, hm, (const short*)smem, w64lds, lane);
        }
        write_attn(out, row0, kgrp, lrow, 256, accn, accd4, (const float*)(smem + 33792), lane);
    }
}

extern "C" void kernel_launch(void* const* d_in, const int* in_sizes, int n_in,
                              void* d_out, int out_size, void* d_ws, size_t ws_size,
                              hipStream_t stream)
{
    (void)in_sizes; (void)n_in; (void)out_size; (void)ws_size;
    const float* own   = (const float*)d_in[0];
    const float* ally  = (const float*)d_in[1];
    const float* enemy = (const float*)d_in[2];
    const float* Wq    = (const float*)d_in[3];
    const float* bq    = (const float*)d_in[4];
    const float* Wak   = (const float*)d_in[5];
    const float* Wav   = (const float*)d_in[7];
    const float* bav   = (const float*)d_in[8];
    const float* Wek   = (const float*)d_in[9];
    const float* Wev   = (const float*)d_in[11];
    const float* bev   = (const float*)d_in[12];
    const float* Wown  = (const float*)d_in[13];
    const float* bown  = (const float*)d_in[14];

    pack_weights<<<31, 256, 0, stream>>>(Wq, bq, Wak, Wav, bav, Wek, Wev, bev, Wown, bown,
                                         (char*)d_ws);
    TrSFRNNAgent_fused<<<BROWS / 64, 256, 0, stream>>>(own, ally, enemy,
                                                       (const char*)d_ws, (float*)d_out);
}

// Round 6
// 153.120 us; speedup vs baseline: 7.8032x; 1.7556x over previous
//
#include <hip/hip_runtime.h>
#include <hip/hip_bf16.h>
#include <stdint.h>

#define N_AL 9
#define N_EN 10
#define D_OWN 96
#define D_AL 64
#define D_EN 65
#define BROWS 65536

// ws byte layout
#define WS_P0 0        // 48 KB: phase0 frags (16 tiles x 3 ks x 64 lanes x 16B)
#define WS_B0 49152    // 1 KB : bias0 = [bq*QS (128) | bown (128)] f32
#define WS_P1 50176    // 36 KB region: [bpack1 32768][bav 512][pad]
#define WS_P2 87040    // 36 KB region: [bpack2 32768][w64cat 1024][bev 512][pad]
#define REGION 36864

#define QSCALE (0.17677669529663688f * 1.4426950408889634f)  // 1/sqrt(32) * log2(e)

typedef __attribute__((ext_vector_type(8))) short short8;
typedef __attribute__((ext_vector_type(4))) float f32x4;
typedef __attribute__((ext_vector_type(4), aligned(4))) float f32x4u;  // dword-aligned vector load
typedef __attribute__((address_space(1))) const unsigned guint;
typedef __attribute__((address_space(3))) unsigned luint;

static __device__ __forceinline__ unsigned cvtpk(float lo, float hi) {
    unsigned r;
    asm("v_cvt_pk_bf16_f32 %0, %1, %2" : "=v"(r) : "v"(lo), "v"(hi));
    return r;
}
static __device__ __forceinline__ float bflo(unsigned u) { return __builtin_bit_cast(float, u << 16); }
static __device__ __forceinline__ float bfhi(unsigned u) { return __builtin_bit_cast(float, u & 0xffff0000u); }

static __device__ __forceinline__ short8 pack8(f32x4 a, f32x4 b) {
    union { unsigned u[4]; short8 s; } t;
    t.u[0] = cvtpk(a[0], a[1]); t.u[1] = cvtpk(a[2], a[3]);
    t.u[2] = cvtpk(b[0], b[1]); t.u[3] = cvtpk(b[2], b[3]);
    return t.s;
}
static __device__ __forceinline__ short f2bf1(float x) { return (short)(cvtpk(x, 0.0f) & 0xffffu); }

// ---- DPP via compiler intrinsic (hazard-safe: compiler inserts wait states) ----
// ctrl: quad_perm[1,0,3,2]=0xB1, quad_perm[2,3,0,1]=0x4E, row_half_mirror=0x141, row_mirror=0x140
template <int CTRL>
static __device__ __forceinline__ float dpp_mov(float x) {
    return __builtin_bit_cast(float,
        __builtin_amdgcn_update_dpp(0, __builtin_bit_cast(int, x), CTRL, 0xf, 0xf, true));
}
static __device__ __forceinline__ float reduce16(float x) {   // sum over 16-lane group, VALU-rate
    x += dpp_mov<0xB1>(x);    // += lane^1
    x += dpp_mov<0x4E>(x);    // += lane^2  (quad uniform)
    x += dpp_mov<0x141>(x);   // += other quad in half (8-lane uniform)
    x += dpp_mov<0x140>(x);   // += other half of row  (16-lane uniform)
    return x;
}

// ---------------- weight packing kernel (runs once per launch, 31 blocks) ----------------
__global__ void pack_weights(const float* __restrict__ Wq,  const float* __restrict__ bq,
                             const float* __restrict__ Wak, const float* __restrict__ Wav,
                             const float* __restrict__ bav, const float* __restrict__ Wek,
                             const float* __restrict__ Wev, const float* __restrict__ bev,
                             const float* __restrict__ Wown,const float* __restrict__ bown,
                             char* __restrict__ ws)
{
    int id = blockIdx.x * 256 + threadIdx.x;
    if (id < 7168) {
        const float *W0, *W1; int KS; short* dst; int f; bool isP0 = false;
        if (id < 3072)      { W0 = Wq;  W1 = Wown; KS = 3; dst = (short*)(ws + WS_P0); f = id; isP0 = true; }
        else if (id < 5120) { W0 = Wak; W1 = Wav;  KS = 2; dst = (short*)(ws + WS_P1); f = id - 3072; }
        else                { W0 = Wek; W1 = Wev;  KS = 2; dst = (short*)(ws + WS_P2); f = id - 5120; }
        int lane = f & 63, ks = (f >> 6) % KS, tile = f / (KS * 64);
        int col = tile * 16 + (lane & 15), k0 = ks * 32 + (lane >> 4) * 8;
        const float* W = (col < 128) ? W0 : W1;
        float scl = (isP0 && col < 128) ? QSCALE : 1.0f;   // fold softmax scale*log2e into Wq
        int c = col & 127;
        short8 v;
        #pragma unroll
        for (int i = 0; i < 8; ++i) v[i] = f2bf1(W[(k0 + i) * 128 + c] * scl);
        *(short8*)(dst + (size_t)f * 8) = v;
    } else if (id < 7936) {
        int j = id - 7168;
        float* b0  = (float*)(ws + WS_B0);
        float* bV1 = (float*)(ws + WS_P1 + 32768);
        float* w64 = (float*)(ws + WS_P2 + 32768);
        float* bV2 = (float*)(ws + WS_P2 + 33792);
        if      (j < 128) b0[j] = bq[j] * QSCALE;
        else if (j < 256) b0[j] = bown[j - 128];
        else if (j < 384) w64[j - 256] = Wek[64 * 128 + (j - 256)];
        else if (j < 512) w64[j - 256] = Wev[64 * 128 + (j - 384)];
        else if (j < 640) bV1[j - 512] = bav[j - 512];
        else              bV2[j - 640] = bev[j - 640];
    }
}

// ---------------- 36 KB linear global->LDS stage (16B direct-to-LDS) ----------------
static __device__ __forceinline__ void stage36(const char* src, char* smem, int wid, int lane) {
    #pragma unroll
    for (int c = 0; c < 9; ++c) {
        int off = (wid * 9 + c) * 1024;
        __builtin_amdgcn_global_load_lds((guint*)(src + off + lane * 16),
                                         (luint*)(smem + off), 16, 0, 0);
    }
}

// ---------------- raw A-row loads (prefetchable) ----------------
static __device__ __forceinline__ void loadAllyRaw(const float* __restrict__ ally,
                                                   int arow, int kgrp, int e, f32x4* v) {
    const float* ap = ally + ((size_t)arow * N_AL + e) * D_AL + kgrp * 8;
    v[0] = *(const f32x4*)(ap);
    v[1] = *(const f32x4*)(ap + 4);
    v[2] = *(const f32x4*)(ap + 32);
    v[3] = *(const f32x4*)(ap + 36);
}

static __device__ __forceinline__ void loadEnemyRaw(const float* __restrict__ enemy,
                                                    int arow, int row0, int kgrp, int e,
                                                    f32x4* v, float* x64) {
    const float* ap = enemy + ((size_t)arow * N_EN + e) * D_EN + kgrp * 8;
    v[0] = *(const f32x4u*)(ap);
    v[1] = *(const f32x4u*)(ap + 4);
    v[2] = *(const f32x4u*)(ap + 32);
    v[3] = *(const f32x4u*)(ap + 36);
    #pragma unroll
    for (int r = 0; r < 4; ++r)
        x64[r] = enemy[((size_t)(row0 + kgrp * 4 + r) * N_EN + e) * D_EN + 64];
}

// ---------------- one entity's K-attn-V update (head-pair split, sharded denom) ----------------
template <bool X64>
static __device__ __forceinline__ void entity_step(
    const short8* afr, const float* x64, const unsigned* qq,
    float (&accn)[2][4][4], float (&accd4)[4], const float (&hm)[4],
    const short* bpk, const float* w64lds, int lane)
{
    const int lrow = lane & 15;
    #pragma unroll
    for (int hp = 0; hp < 2; ++hp) {
        f32x4 acc4[4];
        #pragma unroll
        for (int j = 0; j < 4; ++j) {
            if (X64) {
                float w = w64lds[(4 * hp + j) * 16 + lrow];
                #pragma unroll
                for (int r = 0; r < 4; ++r) acc4[j][r] = x64[r] * w;
            } else {
                #pragma unroll
                for (int r = 0; r < 4; ++r) acc4[j][r] = 0.0f;
            }
        }
        #pragma unroll
        for (int ks = 0; ks < 2; ++ks)
            #pragma unroll
            for (int j = 0; j < 4; ++j) {
                short8 bfr = *(const short8*)(bpk + (size_t)(((4 * hp + j) * 2 + ks) * 64 + lane) * 8);
                acc4[j] = __builtin_amdgcn_mfma_f32_16x16x32_bf16(afr[ks], bfr, acc4[j], 0, 0, 0);
            }
        float p0[4], p1[4];
        #pragma unroll
        for (int r = 0; r < 4; ++r) { p0[r] = 0.0f; p1[r] = 0.0f; }
        #pragma unroll
        for (int j = 0; j < 4; ++j) {
            int t = 4 * hp + j;
            float* pp = (j < 2) ? p0 : p1;
            #pragma unroll
            for (int pr = 0; pr < 2; ++pr) {
                unsigned u = qq[t * 2 + pr];
                pp[2 * pr]     += bflo(u) * acc4[j][2 * pr];
                pp[2 * pr + 1] += bfhi(u) * acc4[j][2 * pr + 1];
            }
        }
        float s0[4], s1[4];
        #pragma unroll
        for (int r = 0; r < 4; ++r) {
            s0[r] = __builtin_amdgcn_exp2f(reduce16(p0[r]));   // DPP reduce: VALU-rate, no DS pipe
            s1[r] = __builtin_amdgcn_exp2f(reduce16(p1[r]));
            accd4[r] += hm[2 * hp] * s0[r] + hm[2 * hp + 1] * s1[r];  // lane keeps head lane&3 only
        }
        #pragma unroll
        for (int j = 0; j < 4; ++j) {
            if (X64) {
                float w = w64lds[128 + (4 * hp + j) * 16 + lrow];
                #pragma unroll
                for (int r = 0; r < 4; ++r) acc4[j][r] = x64[r] * w;
            } else {
                #pragma unroll
                for (int r = 0; r < 4; ++r) acc4[j][r] = 0.0f;
            }
        }
        #pragma unroll
        for (int ks = 0; ks < 2; ++ks)
            #pragma unroll
            for (int j = 0; j < 4; ++j) {
                short8 bfr = *(const short8*)(bpk + (size_t)(((8 + 4 * hp + j) * 2 + ks) * 64 + lane) * 8);
                acc4[j] = __builtin_amdgcn_mfma_f32_16x16x32_bf16(afr[ks], bfr, acc4[j], 0, 0, 0);
            }
        #pragma unroll
        for (int j = 0; j < 4; ++j) {
            const float* s = (j < 2) ? s0 : s1;
            #pragma unroll
            for (int r = 0; r < 4; ++r) accn[hp][j][r] += s[r] * acc4[j][r];
        }
    }
}

static __device__ __forceinline__ void write_attn(float* __restrict__ out, int row0, int kgrp,
                                                  int lrow, int coloff,
                                                  const float (&accn)[2][4][4],
                                                  const float (&accd4)[4],
                                                  const float* bVlds)
{
    // gather all 4 heads' denominators via quad broadcast (denom for head h lives on lane&3==h)
    float inv[4][4];
    #pragma unroll
    for (int r = 0; r < 4; ++r) {
        inv[0][r] = __builtin_amdgcn_rcpf(dpp_mov<0x00>(accd4[r]));   // quad_perm[0,0,0,0]
        inv[1][r] = __builtin_amdgcn_rcpf(dpp_mov<0x55>(accd4[r]));   // quad_perm[1,1,1,1]
        inv[2][r] = __builtin_amdgcn_rcpf(dpp_mov<0xAA>(accd4[r]));   // quad_perm[2,2,2,2]
        inv[3][r] = __builtin_amdgcn_rcpf(dpp_mov<0xFF>(accd4[r]));   // quad_perm[3,3,3,3]
    }
    #pragma unroll
    for (int hp = 0; hp < 2; ++hp)
        #pragma unroll
        for (int j = 0; j < 4; ++j) {
            int col = (4 * hp + j) * 16 + lrow;
            float bb = bVlds[col];
            #pragma unroll
            for (int r = 0; r < 4; ++r)
                out[(size_t)(row0 + kgrp * 4 + r) * 384 + coloff + col] =
                    accn[hp][j][r] * inv[2 * hp + (j >> 1)][r] + bb;
        }
}

// ---------------- main fused kernel: 4 waves x 16 rows, grid 1024 = 4 blocks/CU resident ----------------
__global__ __launch_bounds__(256, 4)
void TrSFRNNAgent_fused(const float* __restrict__ own,
                        const float* __restrict__ ally,
                        const float* __restrict__ enemy,
                        const char* __restrict__ ws,
                        float* __restrict__ out)
{
    __shared__ __align__(16) char smem[REGION];
    const int tid = threadIdx.x, lane = tid & 63, wid = tid >> 6;
    const int row0 = blockIdx.x * 64 + wid * 16;
    const int lrow = lane & 15, kgrp = lane >> 4;
    const int arow = row0 + lrow;
    float hm[4];
    #pragma unroll
    for (int h = 0; h < 4; ++h) hm[h] = ((lane & 3) == h) ? 1.0f : 0.0f;

    // stage phase-1 weights into LDS; hides under phase-0 compute
    stage36(ws + WS_P1, smem, wid, lane);

    // prefetch ally entity 0 (consumed after phase 0)
    f32x4 prefA[4];
    loadAllyRaw(ally, arow, kgrp, 0, prefA);

    // ---------------- Phase 0: own_obs -> q (bf16, scale folded) + own_feature ----------------
    unsigned qq[16];
    {
        short8 afr0[3];
        {
            const float* ap = own + (size_t)arow * D_OWN + kgrp * 8;
            #pragma unroll
            for (int ks = 0; ks < 3; ++ks) {
                f32x4 a = *(const f32x4*)(ap + ks * 32);
                f32x4 b = *(const f32x4*)(ap + ks * 32 + 4);
                afr0[ks] = pack8(a, b);
            }
        }
        const short* bp0 = (const short*)(ws + WS_P0);
        const float* b0  = (const float*)(ws + WS_B0);
        #pragma unroll
        for (int pass = 0; pass < 2; ++pass) {       // 8 tiles per pass: half the acc regs
            f32x4 acc[8];
            #pragma unroll
            for (int t = 0; t < 8; ++t)
                #pragma unroll
                for (int r = 0; r < 4; ++r) acc[t][r] = 0.0f;
            #pragma unroll
            for (int ks = 0; ks < 3; ++ks)
                #pragma unroll
                for (int t = 0; t < 8; ++t) {
                    short8 bfr = *(const short8*)(bp0 + (size_t)(((pass * 8 + t) * 3 + ks) * 64 + lane) * 8);
                    acc[t] = __builtin_amdgcn_mfma_f32_16x16x32_bf16(afr0[ks], bfr, acc[t], 0, 0, 0);
                }
            if (pass == 0) {
                #pragma unroll
                for (int t = 0; t < 8; ++t) {
                    float bb = b0[t * 16 + lrow];   // pre-scaled
                    qq[t * 2]     = cvtpk(acc[t][0] + bb, acc[t][1] + bb);
                    qq[t * 2 + 1] = cvtpk(acc[t][2] + bb, acc[t][3] + bb);
                }
            } else {
                #pragma unroll
                for (int t = 0; t < 8; ++t) {
                    float bb = b0[128 + t * 16 + lrow];
                    #pragma unroll
                    for (int r = 0; r < 4; ++r)
                        out[(size_t)(row0 + kgrp * 4 + r) * 384 + t * 16 + lrow] = acc[t][r] + bb;
                }
            }
        }
    }
    __syncthreads();   // phase-1 LDS ready

    // ---------------- Phase 1: allies (rolled, 1-deep register pipeline) ----------------
    f32x4 prefE[4]; float x64e[4];
    {
        float accn[2][4][4] = {{{0}}}; float accd4[4] = {0, 0, 0, 0};
        #pragma unroll 1
        for (int e = 0; e < N_AL; ++e) {
            short8 afr[2];
            afr[0] = pack8(prefA[0], prefA[1]);
            afr[1] = pack8(prefA[2], prefA[3]);
            if (e + 1 < N_AL) loadAllyRaw(ally, arow, kgrp, e + 1, prefA);
            entity_step<false>(afr, nullptr, qq, accn, accd4, hm, (const short*)smem, nullptr, lane);
        }
        loadEnemyRaw(enemy, arow, row0, kgrp, 0, prefE, x64e);   // hides under stores+barriers
        write_attn(out, row0, kgrp, lrow, 128, accn, accd4, (const float*)(smem + 32768));
    }
    __syncthreads();                       // all waves done reading phase-1 LDS
    stage36(ws + WS_P2, smem, wid, lane);  // re-stage for phase 2 (prefE survives in regs)
    __syncthreads();

    // ---------------- Phase 2: enemies (K=64 staged + k64 rank-1 via acc init) ----------------
    {
        const float* w64lds = (const float*)(smem + 32768);
        float accn[2][4][4] = {{{0}}}; float accd4[4] = {0, 0, 0, 0};
        #pragma unroll 1
        for (int e = 0; e < N_EN; ++e) {
            short8 afr[2];
            afr[0] = pack8(prefE[0], prefE[1]);
            afr[1] = pack8(prefE[2], prefE[3]);
            float xc[4];
            #pragma unroll
            for (int r = 0; r < 4; ++r) xc[r] = x64e[r];
            if (e + 1 < N_EN) loadEnemyRaw(enemy, arow, row0, kgrp, e + 1, prefE, x64e);
            entity_step<true>(afr, xc, qq, accn, accd4, hm, (const short*)smem, w64lds, lane);
        }
        write_attn(out, row0, kgrp, lrow, 256, accn, accd4, (const float*)(smem + 33792));
    }
}

extern "C" void kernel_launch(void* const* d_in, const int* in_sizes, int n_in,
                              void* d_out, int out_size, void* d_ws, size_t ws_size,
                              hipStream_t stream)
{
    (void)in_sizes; (void)n_in; (void)out_size; (void)ws_size;
    const float* own   = (const float*)d_in[0];
    const float* ally  = (const float*)d_in[1];
    const float* enemy = (const float*)d_in[2];
    const float* Wq    = (const float*)d_in[3];
    const float* bq    = (const float*)d_in[4];
    const float* Wak   = (const float*)d_in[5];
    const float* Wav   = (const float*)d_in[7];
    const float* bav   = (const float*)d_in[8];
    const float* Wek   = (const float*)d_in[9];
    const float* Wev   = (const float*)d_in[11];
    const float* bev   = (const float*)d_in[12];
    const float* Wown  = (const float*)d_in[13];
    const float* bown  = (const float*)d_in[14];

    pack_weights<<<31, 256, 0, stream>>>(Wq, bq, Wak, Wav, bav, Wek, Wev, bev, Wown, bown,
                                         (char*)d_ws);
    TrSFRNNAgent_fused<<<BROWS / 64, 256, 0, stream>>>(own, ally, enemy,
                                                       (const char*)d_ws, (float*)d_out);
}